// Round 14
// baseline (510.333 us; speedup 1.0000x reference)
//
#include <hip/hip_runtime.h>
#include <hip/hip_fp16.h>
#include <math.h>

// Problem constants
constexpr int D     = 64;
constexpr int H     = 14;
constexpr int HP2   = 8;     // half2 stride per node row (32B)
constexpr int P     = 16;
constexpr int LATc  = 7;
constexpr int OUTW  = 30;
constexpr float SP_INV_1 = 0.5413248546129181f;
constexpr int BLK       = 256;
// 2 blocks/CU on 256 CUs = 512. __launch_bounds__(256,4) guarantees capacity
// for 4 blocks/CU, so 512 co-resident blocks have a 2x margin -> no deadlock
// even with maximally uneven CP placement.
constexpr int MEGA_BLKS = 512;

// Packed fp16 atomic add (memory-side RMW; header overload missing in ROCm 7.2)
__device__ __forceinline__ void pk_atomic_add_f16(__half2* addr, __half2 val) {
    unsigned int bits = *reinterpret_cast<unsigned int*>(&val);
    asm volatile("global_atomic_pk_add_f16 %0, %1, off"
                 :: "v"(addr), "v"(bits) : "memory");
}

// Grid barrier: block drain -> thread-0 {agent release fence (L2 writeback),
// arrive, spin, agent acquire fence (L2 invalidate)} -> block resume.
// Plain cached loads/stores are coherent across it (one cache-maintenance op
// per block per barrier, amortized — R12 lesson).
__device__ __forceinline__ void grid_bar(int* ctr, int target) {
    __syncthreads();
    if (threadIdx.x == 0) {
        __threadfence();    // agent release: wbl2 + waitcnt
        __hip_atomic_fetch_add(ctr, 1, __ATOMIC_RELAXED, __HIP_MEMORY_SCOPE_AGENT);
        while (__hip_atomic_load(ctr, __ATOMIC_RELAXED, __HIP_MEMORY_SCOPE_AGENT) < target)
            __builtin_amdgcn_s_sleep(2);
        __threadfence();    // agent acquire: inv
    }
    __syncthreads();
}

// ---------------- D1: XW = fp16(X @ W1); zero Y1/Y2; init barriers ---------
// 2 threads per node (proven R10). Kernel-end implicit flush makes XW/zeros
// coherent for D2 (proven by R7/R10/R11 passing).
__global__ void dense_xw_kernel(const float* __restrict__ X,
                                const float* __restrict__ W1,
                                __half2* __restrict__ XW,
                                __half2* __restrict__ Y1,
                                __half2* __restrict__ Y2,
                                int* __restrict__ bar, int N) {
    if (blockIdx.x == 0 && threadIdx.x < 8) bar[threadIdx.x] = 0;
    __shared__ float w[D * H];
    for (int i = threadIdx.x; i < D * H; i += blockDim.x) w[i] = W1[i];
    __syncthreads();
    int t = blockIdx.x * blockDim.x + threadIdx.x;
    int n = t >> 1;
    int half = t & 1;
    if (n >= N) return;

    float acc[H];
#pragma unroll
    for (int j = 0; j < H; ++j) acc[j] = 0.f;
    const float4* xr = reinterpret_cast<const float4*>(X + (size_t)n * D) + half * 8;
#pragma unroll
    for (int d4 = 0; d4 < 8; ++d4) {
        float4 x = xr[d4];
        float xs[4] = {x.x, x.y, x.z, x.w};
#pragma unroll
        for (int k = 0; k < 4; ++k) {
            int d = half * 32 + d4 * 4 + k;
#pragma unroll
            for (int j = 0; j < H; ++j) acc[j] = fmaf(xs[k], w[d * H + j], acc[j]);
        }
    }
#pragma unroll
    for (int j = 0; j < H; ++j) acc[j] += __shfl_xor(acc[j], 1);

    __half2 ov[4];
    if (half == 0) {
        ov[0] = __floats2half2_rn(acc[0], acc[1]);
        ov[1] = __floats2half2_rn(acc[2], acc[3]);
        ov[2] = __floats2half2_rn(acc[4], acc[5]);
        ov[3] = __floats2half2_rn(acc[6], acc[7]);
    } else {
        ov[0] = __floats2half2_rn(acc[8], acc[9]);
        ov[1] = __floats2half2_rn(acc[10], acc[11]);
        ov[2] = __floats2half2_rn(acc[12], acc[13]);
        ov[3] = __floats2half2_rn(0.f, 0.f);
    }
    reinterpret_cast<float4*>(XW + (size_t)n * HP2)[half] = *reinterpret_cast<float4*>(ov);
    float4 z = make_float4(0.f, 0.f, 0.f, 0.f);
    reinterpret_cast<float4*>(Y1 + (size_t)n * HP2)[half] = z;
    reinterpret_cast<float4*>(Y2 + (size_t)n * HP2)[half] = z;
}

// ---------------- D2: mega = spmm1 | bar | hw | bar | spmm2 | bar | final --
__global__ __launch_bounds__(BLK, 4) void mega_kernel(
        const __half2* __restrict__ XW,
        const int* __restrict__ rows,
        const int* __restrict__ cols,
        const float* __restrict__ vals,
        const float* __restrict__ W2,
        const float* __restrict__ Wd1,
        const float* __restrict__ bd1,
        const float* __restrict__ Wd2,
        const float* __restrict__ bd2,
        __half2* __restrict__ HW,
        __half2* __restrict__ Y1,
        __half2* __restrict__ Y2,
        float* __restrict__ out,
        int* __restrict__ bar,
        int N, int E) {
    __shared__ float w2s[H * H], wd1s[H * H], wd2s[H * P], b1s[H], b2s[P];
    for (int i = threadIdx.x; i < H * H; i += BLK) { w2s[i] = W2[i]; wd1s[i] = Wd1[i]; }
    for (int i = threadIdx.x; i < H * P; i += BLK) wd2s[i] = Wd2[i];
    if (threadIdx.x < H) b1s[threadIdx.x] = bd1[threadIdx.x];
    if (threadIdx.x < P) b2s[threadIdx.x] = bd2[threadIdx.x];
    __syncthreads();

    const int tid = blockIdx.x * BLK + threadIdx.x;
    const int nth = gridDim.x * BLK;
    const long long tot = (long long)E * 8;

    // ---- P1: spmm1: Y1 += vals * XW[cols] ----
    for (long long i = tid; i < tot; i += nth) {
        int e = (int)(i >> 3), f = (int)(i & 7);
        if (f < 7) {
            int r = rows[e], c = cols[e];
            float v = vals[e];
            float2 xf = __half22float2(XW[c * HP2 + f]);
            __half2 p = __floats2half2_rn(v * xf.x, v * xf.y);
            pk_atomic_add_f16(&Y1[r * HP2 + f], p);
        }
    }
    grid_bar(&bar[0], gridDim.x);

    // ---- P2: HW = fp16(relu(Y1) @ W2) (plain loads; caches inv'd) ----
    for (int n = tid; n < N; n += nth) {
        const float4* yr4 = reinterpret_cast<const float4*>(Y1 + (size_t)n * HP2);
        float4 ya = yr4[0], yb = yr4[1];
        __half2 yh[HP2];
        *reinterpret_cast<float4*>(&yh[0]) = ya;
        *reinterpret_cast<float4*>(&yh[4]) = yb;
        float h[H];
#pragma unroll
        for (int k = 0; k < 7; ++k) {
            float2 t = __half22float2(yh[k]);
            h[2 * k]     = fmaxf(t.x, 0.f);
            h[2 * k + 1] = fmaxf(t.y, 0.f);
        }
        __half2 ov[HP2];
#pragma unroll
        for (int j = 0; j < 7; ++j) {
            float a0 = 0.f, a1 = 0.f;
#pragma unroll
            for (int i2 = 0; i2 < H; ++i2) {
                a0 = fmaf(h[i2], w2s[i2 * H + 2 * j], a0);
                a1 = fmaf(h[i2], w2s[i2 * H + 2 * j + 1], a1);
            }
            ov[j] = __floats2half2_rn(a0, a1);
        }
        ov[7] = __floats2half2_rn(0.f, 0.f);
        float4* dst = reinterpret_cast<float4*>(HW + (size_t)n * HP2);
        dst[0] = *reinterpret_cast<float4*>(&ov[0]);
        dst[1] = *reinterpret_cast<float4*>(&ov[4]);
    }
    grid_bar(&bar[1], gridDim.x);

    // ---- P3: spmm2: Y2 += vals * HW[cols] ----
    for (long long i = tid; i < tot; i += nth) {
        int e = (int)(i >> 3), f = (int)(i & 7);
        if (f < 7) {
            int r = rows[e], c = cols[e];
            float v = vals[e];
            float2 xf = __half22float2(HW[c * HP2 + f]);
            __half2 p = __floats2half2_rn(v * xf.x, v * xf.y);
            pk_atomic_add_f16(&Y2[r * HP2 + f], p);
        }
    }
    grid_bar(&bar[2], gridDim.x);

    // ---- P4: final heads -> out ----
    for (int n = tid; n < N; n += nth) {
        const float4* yr4 = reinterpret_cast<const float4*>(Y2 + (size_t)n * HP2);
        float4 ya = yr4[0], yb = yr4[1];
        __half2 yh[HP2];
        *reinterpret_cast<float4*>(&yh[0]) = ya;
        *reinterpret_cast<float4*>(&yh[4]) = yb;
        float h[H];
#pragma unroll
        for (int k = 0; k < 7; ++k) {
            float2 t = __half22float2(yh[k]);
            h[2 * k]     = fmaxf(t.x, 0.f);
            h[2 * k + 1] = fmaxf(t.y, 0.f);
        }
        float pd[H];
#pragma unroll
        for (int j = 0; j < H; ++j) {
            float a = b1s[j];
#pragma unroll
            for (int i2 = 0; i2 < H; ++i2) a = fmaf(h[i2], wd1s[i2 * H + j], a);
            pd[j] = tanhf(a);
        }
        float pp[P];
#pragma unroll
        for (int j = 0; j < P; ++j) {
            float a = b2s[j];
#pragma unroll
            for (int i2 = 0; i2 < H; ++i2) a = fmaf(h[i2], wd2s[i2 * P + j], a);
            pp[j] = tanhf(a);
        }
        float* o = out + (size_t)n * OUTW;
#pragma unroll
        for (int k = 0; k < LATc; ++k) o[k] = pd[k];
#pragma unroll
        for (int k = 0; k < LATc; ++k) {
            float x = pd[LATc + k] + SP_INV_1;
            o[LATc + k] = log1pf(expf(x));
        }
#pragma unroll
        for (int k = 0; k < H; ++k) o[14 + k] = pp[k];
        o[28] = pp[14];
        o[29] = pp[15];
    }
}

extern "C" void kernel_launch(void* const* d_in, const int* in_sizes, int n_in,
                              void* d_out, int out_size, void* d_ws, size_t ws_size,
                              hipStream_t stream) {
    const float* X    = (const float*)d_in[0];
    const int*   rows = (const int*)d_in[1];
    const int*   cols = (const int*)d_in[2];
    const float* vals = (const float*)d_in[3];
    const float* W1   = (const float*)d_in[4];
    const float* W2   = (const float*)d_in[5];
    const float* Wd1  = (const float*)d_in[6];
    const float* bd1  = (const float*)d_in[7];
    const float* Wd2  = (const float*)d_in[8];
    const float* bd2  = (const float*)d_in[9];
    float* out = (float*)d_out;

    const int N = in_sizes[0] / D;   // 100000
    const int E = in_sizes[1];       // 1000000

    // workspace: XW | HW | Y1 | Y2 (half2 rows, 32B/node) | bar[8]
    __half2* XW = (__half2*)d_ws;
    __half2* HW = XW + (size_t)N * HP2;
    __half2* Y1 = HW + (size_t)N * HP2;
    __half2* Y2 = Y1 + (size_t)N * HP2;
    int* bar = (int*)(Y2 + (size_t)N * HP2);

    int blkN2 = (2 * N + 255) / 256;

    dense_xw_kernel<<<blkN2, 256, 0, stream>>>(X, W1, XW, Y1, Y2, bar, N);
    mega_kernel<<<MEGA_BLKS, BLK, 0, stream>>>(XW, rows, cols, vals, W2,
                                               Wd1, bd1, Wd2, bd2,
                                               HW, Y1, Y2, out, bar, N, E);
}

// Round 15
// 218.389 us; speedup vs baseline: 2.3368x; 2.3368x over previous
//
#include <hip/hip_runtime.h>
#include <hip/hip_fp16.h>
#include <math.h>

// Problem constants
constexpr int D     = 64;
constexpr int H     = 14;
constexpr int HP2   = 8;     // half2 stride per node row (32B)
constexpr int P     = 16;
constexpr int LATc  = 7;
constexpr int OUTW  = 30;
constexpr float SP_INV_1 = 0.5413248546129181f;

// Packed fp16 atomic add (memory-side RMW; header overload missing in ROCm 7.2)
__device__ __forceinline__ void pk_atomic_add_f16(__half2* addr, __half2 val) {
    unsigned int bits = *reinterpret_cast<unsigned int*>(&val);
    asm volatile("global_atomic_pk_add_f16 %0, %1, off"
                 :: "v"(addr), "v"(bits) : "memory");
}

// ---------------- D1: XW = fp16(X @ W1); zero Y1/Y2 ------------------------
// 2 threads per node (proven R10).
__global__ void dense_xw_kernel(const float* __restrict__ X,
                                const float* __restrict__ W1,
                                __half2* __restrict__ XW,
                                __half2* __restrict__ Y1,
                                __half2* __restrict__ Y2, int N) {
    __shared__ float w[D * H];
    for (int i = threadIdx.x; i < D * H; i += blockDim.x) w[i] = W1[i];
    __syncthreads();
    int t = blockIdx.x * blockDim.x + threadIdx.x;
    int n = t >> 1;
    int half = t & 1;
    if (n >= N) return;

    float acc[H];
#pragma unroll
    for (int j = 0; j < H; ++j) acc[j] = 0.f;
    const float4* xr = reinterpret_cast<const float4*>(X + (size_t)n * D) + half * 8;
#pragma unroll
    for (int d4 = 0; d4 < 8; ++d4) {
        float4 x = xr[d4];
        float xs[4] = {x.x, x.y, x.z, x.w};
#pragma unroll
        for (int k = 0; k < 4; ++k) {
            int d = half * 32 + d4 * 4 + k;
#pragma unroll
            for (int j = 0; j < H; ++j) acc[j] = fmaf(xs[k], w[d * H + j], acc[j]);
        }
    }
#pragma unroll
    for (int j = 0; j < H; ++j) acc[j] += __shfl_xor(acc[j], 1);

    __half2 ov[4];
    if (half == 0) {
        ov[0] = __floats2half2_rn(acc[0], acc[1]);
        ov[1] = __floats2half2_rn(acc[2], acc[3]);
        ov[2] = __floats2half2_rn(acc[4], acc[5]);
        ov[3] = __floats2half2_rn(acc[6], acc[7]);
    } else {
        ov[0] = __floats2half2_rn(acc[8], acc[9]);
        ov[1] = __floats2half2_rn(acc[10], acc[11]);
        ov[2] = __floats2half2_rn(acc[12], acc[13]);
        ov[3] = __floats2half2_rn(0.f, 0.f);
    }
    reinterpret_cast<float4*>(XW + (size_t)n * HP2)[half] = *reinterpret_cast<float4*>(ov);
    float4 z = make_float4(0.f, 0.f, 0.f, 0.f);
    reinterpret_cast<float4*>(Y1 + (size_t)n * HP2)[half] = z;
    reinterpret_cast<float4*>(Y2 + (size_t)n * HP2)[half] = z;
}

// ---------------- D2: spmm1: Y1 += vals * XW[cols] (proven 51.5us) ---------
__global__ void spmm_pk_kernel(const __half2* __restrict__ F,
                               const int* __restrict__ rows,
                               const int* __restrict__ cols,
                               const float* __restrict__ vals,
                               __half2* __restrict__ Y, int E) {
    int idx = blockIdx.x * blockDim.x + threadIdx.x;
    int e = idx >> 3;
    int f = idx & 7;
    if (e >= E || f >= 7) return;
    int r = rows[e];
    int c = cols[e];
    float v = vals[e];
    float2 xf = __half22float2(F[c * HP2 + f]);
    __half2 p = __floats2half2_rn(v * xf.x, v * xf.y);
    pk_atomic_add_f16(&Y[r * HP2 + f], p);
}

// ---------------- D3: spmm2: Y2 += vals * relu(Y1[cols]) -------------------
// spmm(relu(Y1) @ W2) == spmm(relu(Y1)) @ W2 : the @W2 moves to final_kernel,
// relu is applied in-register at the gather. Eliminates the dense_hw dispatch.
__global__ void spmm_relu_kernel(const __half2* __restrict__ Y1,
                                 const int* __restrict__ rows,
                                 const int* __restrict__ cols,
                                 const float* __restrict__ vals,
                                 __half2* __restrict__ Y2, int E) {
    int idx = blockIdx.x * blockDim.x + threadIdx.x;
    int e = idx >> 3;
    int f = idx & 7;
    if (e >= E || f >= 7) return;
    int r = rows[e];
    int c = cols[e];
    float v = vals[e];
    float2 xf = __half22float2(Y1[c * HP2 + f]);
    __half2 p = __floats2half2_rn(v * fmaxf(xf.x, 0.f), v * fmaxf(xf.y, 0.f));
    pk_atomic_add_f16(&Y2[r * HP2 + f], p);
}

// ---------------- D4: final: h2 = relu(Z @ W2); tanh heads -> out ----------
__global__ __launch_bounds__(256) void final_kernel(
        const __half2* __restrict__ Z,       // = spmm(relu(Y1))
        const float* __restrict__ W2,
        const float* __restrict__ Wd1,
        const float* __restrict__ bd1,
        const float* __restrict__ Wd2,
        const float* __restrict__ bd2,
        float* __restrict__ out, int N) {
    __shared__ float w2[H * H], wd1[H * H], wd2[H * P], b1[H], b2[P];
    __shared__ float so[256 * OUTW];
    for (int i = threadIdx.x; i < H * H; i += 256) { w2[i] = W2[i]; wd1[i] = Wd1[i]; }
    for (int i = threadIdx.x; i < H * P; i += 256) wd2[i] = Wd2[i];
    if (threadIdx.x < H) b1[threadIdx.x] = bd1[threadIdx.x];
    if (threadIdx.x < P) b2[threadIdx.x] = bd2[threadIdx.x];
    __syncthreads();

    int base = blockIdx.x * 256;
    int n = base + threadIdx.x;
    if (n < N) {
        const float4* zr4 = reinterpret_cast<const float4*>(Z + (size_t)n * HP2);
        float4 za = zr4[0], zb = zr4[1];
        __half2 zh[HP2];
        *reinterpret_cast<float4*>(&zh[0]) = za;
        *reinterpret_cast<float4*>(&zh[4]) = zb;
        float z[H];
#pragma unroll
        for (int k = 0; k < 7; ++k) {
            float2 t = __half22float2(zh[k]);
            z[2 * k]     = t.x;
            z[2 * k + 1] = t.y;
        }
        // h2 = relu(Z @ W2)
        float h[H];
#pragma unroll
        for (int j = 0; j < H; ++j) {
            float a = 0.f;
#pragma unroll
            for (int i = 0; i < H; ++i) a = fmaf(z[i], w2[i * H + j], a);
            h[j] = fmaxf(a, 0.f);
        }
        float* so_row = &so[threadIdx.x * OUTW];
        float pd7[LATc];
#pragma unroll
        for (int j = 0; j < H; ++j) {
            float a = b1[j];
#pragma unroll
            for (int i = 0; i < H; ++i) a = fmaf(h[i], wd1[i * H + j], a);
            float t = tanhf(a);
            if (j < LATc) so_row[j] = t;
            else pd7[j - LATc] = t;
        }
#pragma unroll
        for (int k = 0; k < LATc; ++k) {
            float x = pd7[k] + SP_INV_1;
            so_row[LATc + k] = log1pf(expf(x));
        }
#pragma unroll
        for (int j = 0; j < P; ++j) {
            float a = b2[j];
#pragma unroll
            for (int i = 0; i < H; ++i) a = fmaf(h[i], wd2[i * P + j], a);
            so_row[14 + j] = tanhf(a);
        }
    }
    __syncthreads();

    int rowsHere = N - base;
    if (rowsHere > 256) rowsHere = 256;
    if (rowsHere < 0) rowsHere = 0;
    int cnt = rowsHere * OUTW;
    float* obase = out + (size_t)base * OUTW;
    for (int i = threadIdx.x; i < cnt; i += 256) obase[i] = so[i];
}

extern "C" void kernel_launch(void* const* d_in, const int* in_sizes, int n_in,
                              void* d_out, int out_size, void* d_ws, size_t ws_size,
                              hipStream_t stream) {
    const float* X    = (const float*)d_in[0];
    const int*   rows = (const int*)d_in[1];
    const int*   cols = (const int*)d_in[2];
    const float* vals = (const float*)d_in[3];
    const float* W1   = (const float*)d_in[4];
    const float* W2   = (const float*)d_in[5];
    const float* Wd1  = (const float*)d_in[6];
    const float* bd1  = (const float*)d_in[7];
    const float* Wd2  = (const float*)d_in[8];
    const float* bd2  = (const float*)d_in[9];
    float* out = (float*)d_out;

    const int N = in_sizes[0] / D;   // 100000
    const int E = in_sizes[1];       // 1000000

    // workspace (half2 rows, 32B/node): XW | Y1 | Y2
    __half2* XW = (__half2*)d_ws;
    __half2* Y1 = XW + (size_t)N * HP2;
    __half2* Y2 = Y1 + (size_t)N * HP2;

    int blkN  = (N + 255) / 256;
    int blkN2 = (2 * N + 255) / 256;
    long long spmmThreads = (long long)E * 8;
    unsigned blkS = (unsigned)((spmmThreads + 255) / 256);

    dense_xw_kernel<<<blkN2, 256, 0, stream>>>(X, W1, XW, Y1, Y2, N);
    spmm_pk_kernel<<<blkS, 256, 0, stream>>>(XW, rows, cols, vals, Y1, E);
    spmm_relu_kernel<<<blkS, 256, 0, stream>>>(Y1, rows, cols, vals, Y2, E);
    final_kernel<<<blkN, 256, 0, stream>>>(Y2, W2, Wd1, bd1, Wd2, bd2, out, N);
}